// Round 16
// baseline (257.070 us; speedup 1.0000x reference)
//
#include <hip/hip_runtime.h>
#include <hip/hip_bf16.h>
#include <stdint.h>

typedef __attribute__((ext_vector_type(4))) float f32x4;
typedef __attribute__((ext_vector_type(16))) float f32x16;
typedef __attribute__((ext_vector_type(8))) short s16x8;

#define BARRIER() asm volatile("s_barrier" ::: "memory")
#define WAITV4()  asm volatile("s_waitcnt vmcnt(4)" ::: "memory")
#define WAITV0()  asm volatile("s_waitcnt vmcnt(0)" ::: "memory")
#define LGKM0()   asm volatile("s_waitcnt lgkmcnt(0)" ::: "memory")
#define MFMA(a, b, c) __builtin_amdgcn_mfma_f32_16x16x32_bf16((a), (b), (c), 0, 0, 0)
#define MFMA32(a, b, c) __builtin_amdgcn_mfma_f32_32x32x16_bf16((a), (b), (c), 0, 0, 0)

__device__ __forceinline__ ushort f2bf(float f) {
  union { float f; uint32_t u; } v; v.f = f;
  uint32_t r = v.u + 0x7FFFu + ((v.u >> 16) & 1u);
  return (ushort)(r >> 16);
}

__device__ __forceinline__ void gload_lds16(const ushort* g, short* l) {
  __builtin_amdgcn_global_load_lds(
      (const __attribute__((address_space(1))) uint32_t*)g,
      (__attribute__((address_space(3))) uint32_t*)l, 16, 0, 0);
}

// generic bijective XCD chunk swizzle; valid when nwg % 8 == 0, q = nwg/8
__device__ __forceinline__ int xcd_swz(int flat, int q) {
  return (flat & 7) * q + (flat >> 3);
}

// Stage a 128x64 bf16 tile into LDS with 256 threads (4 loads/thread).
// LDS dest linear (global_load_lds requirement); T2 swizzle via permuted
// GLOBAL source 16B-slot: phys(r,s) holds global(r, s ^ (r&7)).
__device__ __forceinline__ void stage128(const ushort* __restrict__ g, int ld,
                                         int row0, int k0, short* lbase, int tid) {
  const int w  = tid >> 6;
  const int l  = tid & 63;
  const int lr = l >> 3;
  const int ls = l & 7;
  const ushort* gp = g + (size_t)(row0 + lr) * ld + k0 + ((ls ^ lr) << 3);
  short* lp = lbase + l * 8;
#pragma unroll
  for (int i = 0; i < 4; ++i) {
    const int R0 = w * 32 + i * 8;
    gload_lds16(gp + (size_t)R0 * ld, lp + R0 * 64);
  }
}

// ---------------- 16x16x32 core (R15, proven) for sp/pv ----------------

__device__ __forceinline__ void gstep(
    const ushort* __restrict__ A, int lda, const ushort* __restrict__ Bt, int ldb,
    int m0, int n0, int nk, int X, short* Ac, short* Bs,
    int tid, int s0, int aro, int bro, f32x4 acc[4][4], bool skipw)
{
  if (X + 1 < nk) { WAITV4(); } else { WAITV0(); }
  BARRIER();

  s16x8 b[4][2], a[4][2];
  if (!skipw) {
#pragma unroll
    for (int ni = 0; ni < 4; ++ni) {
      b[ni][0] = *(const s16x8*)(Bs + bro + ni * 1024 + s0);
      b[ni][1] = *(const s16x8*)(Bs + bro + ni * 1024 + (s0 ^ 32));
    }
#pragma unroll
    for (int mi = 0; mi < 4; ++mi) {
      a[mi][0] = *(const s16x8*)(Ac + aro + mi * 1024 + s0);
      a[mi][1] = *(const s16x8*)(Ac + aro + mi * 1024 + (s0 ^ 32));
    }
    __builtin_amdgcn_s_setprio(1);
#pragma unroll
    for (int mi = 0; mi < 2; ++mi)
#pragma unroll
      for (int ni = 0; ni < 4; ++ni) {
        acc[mi][ni] = MFMA(a[mi][0], b[ni][0], acc[mi][ni]);
        acc[mi][ni] = MFMA(a[mi][1], b[ni][1], acc[mi][ni]);
      }
    __builtin_amdgcn_s_setprio(0);
  }

  LGKM0();
  BARRIER();
  if (X + 1 < nk) stage128(Bt, ldb, n0, (X + 1) * 64, Bs, tid);   // B(X+1)
  if (X + 2 < nk) stage128(A, lda, m0, (X + 2) * 64, Ac, tid);    // A(X+2)
  if (!skipw) {
    __builtin_amdgcn_s_setprio(1);
#pragma unroll
    for (int mi = 0; mi < 2; ++mi)
#pragma unroll
      for (int ni = 0; ni < 4; ++ni) {
        acc[2 + mi][ni] = MFMA(a[2 + mi][0], b[ni][0], acc[2 + mi][ni]);
        acc[2 + mi][ni] = MFMA(a[2 + mi][1], b[ni][1], acc[2 + mi][ni]);
      }
    __builtin_amdgcn_s_setprio(0);
  }
}

__device__ __forceinline__ void gemm_core(
    const ushort* __restrict__ A, int lda, const ushort* __restrict__ Bt, int ldb,
    int m0, int n0, int nk, short* lds, f32x4 acc[4][4], bool skipw = false)
{
  const int tid  = threadIdx.x;
  const int lane = tid & 63, wid = tid >> 6;
  const int wr = wid >> 1, wc = wid & 1;
  const int fr = lane & 15, kg = lane >> 4;
  const int s0  = (kg ^ (fr & 7)) << 3;
  const int aro = (wr * 64 + fr) * 64;
  const int bro = (wc * 64 + fr) * 64;

  short* Ab0 = lds;
  short* Ab1 = lds + 8192;
  short* Bs  = lds + 16384;

#pragma unroll
  for (int i = 0; i < 4; ++i)
#pragma unroll
    for (int j = 0; j < 4; ++j)
      acc[i][j] = (f32x4){0.f, 0.f, 0.f, 0.f};

  stage128(A, lda, m0, 0, Ab0, tid);
  stage128(Bt, ldb, n0, 0, Bs, tid);
  if (nk > 1) stage128(A, lda, m0, 64, Ab1, tid);

#pragma unroll 1
  for (int X = 0; X < nk; X += 2) {
    gstep(A, lda, Bt, ldb, m0, n0, nk, X,     Ab0, Bs, tid, s0, aro, bro, acc, skipw);
    gstep(A, lda, Bt, ldb, m0, n0, nk, X + 1, Ab1, Bs, tid, s0, aro, bro, acc, skipw);
  }
}

// ---------------- 32x32x16 core (qkv): same ledger, faster MFMA pipe -------
// Wave = 64x64 out = 2x2 frags of 32x32x16 (16 MFMA/K-tile vs 32).
// Frag: lane reads row (lane&31), k = ks*16 + (lane>>5)*8; logical 16B-slot
// = ks*2+(lane>>5), phys = slot ^ (row&7) per the staging swizzle.
__device__ __forceinline__ void gstep32(
    const ushort* __restrict__ A, int lda, const ushort* __restrict__ Bt, int ldb,
    int m0, int n0, int nk, int X, short* Ac, short* Bs,
    int tid, const int* sk, int aro, int bro, f32x16 acc[2][2])
{
  if (X + 1 < nk) { WAITV4(); } else { WAITV0(); }
  BARRIER();

  s16x8 a[2][4], b[2][4];
#pragma unroll
  for (int mi = 0; mi < 2; ++mi)
#pragma unroll
    for (int ks = 0; ks < 4; ++ks)
      a[mi][ks] = *(const s16x8*)(Ac + aro + mi * 2048 + sk[ks]);
#pragma unroll
  for (int ni = 0; ni < 2; ++ni)
#pragma unroll
    for (int ks = 0; ks < 4; ++ks)
      b[ni][ks] = *(const s16x8*)(Bs + bro + ni * 2048 + sk[ks]);

  __builtin_amdgcn_s_setprio(1);
#pragma unroll
  for (int ks = 0; ks < 2; ++ks)
#pragma unroll
    for (int mi = 0; mi < 2; ++mi)
#pragma unroll
      for (int ni = 0; ni < 2; ++ni)
        acc[mi][ni] = MFMA32(a[mi][ks], b[ni][ks], acc[mi][ni]);
  __builtin_amdgcn_s_setprio(0);

  LGKM0();
  BARRIER();
  if (X + 1 < nk) stage128(Bt, ldb, n0, (X + 1) * 64, Bs, tid);   // B(X+1)
  if (X + 2 < nk) stage128(A, lda, m0, (X + 2) * 64, Ac, tid);    // A(X+2)
  __builtin_amdgcn_s_setprio(1);
#pragma unroll
  for (int ks = 2; ks < 4; ++ks)
#pragma unroll
    for (int mi = 0; mi < 2; ++mi)
#pragma unroll
      for (int ni = 0; ni < 2; ++ni)
        acc[mi][ni] = MFMA32(a[mi][ks], b[ni][ks], acc[mi][ni]);
  __builtin_amdgcn_s_setprio(0);
}

__device__ __forceinline__ void gemm_core32(
    const ushort* __restrict__ A, int lda, const ushort* __restrict__ Bt, int ldb,
    int m0, int n0, int nk, short* lds, f32x16 acc[2][2])
{
  const int tid  = threadIdx.x;
  const int lane = tid & 63, wid = tid >> 6;
  const int wr = wid >> 1, wc = wid & 1;
  const int r31 = lane & 31, kh = lane >> 5;
  const int r8  = r31 & 7;
  int sk[4];
#pragma unroll
  for (int ks = 0; ks < 4; ++ks) sk[ks] = ((ks * 2 + kh) ^ r8) << 3;
  const int aro = (wr * 64 + r31) * 64;
  const int bro = (wc * 64 + r31) * 64;

  short* Ab0 = lds;
  short* Ab1 = lds + 8192;
  short* Bs  = lds + 16384;

#pragma unroll
  for (int i = 0; i < 2; ++i)
#pragma unroll
    for (int j = 0; j < 2; ++j)
#pragma unroll
      for (int e = 0; e < 16; ++e) acc[i][j][e] = 0.f;

  stage128(A, lda, m0, 0, Ab0, tid);
  stage128(Bt, ldb, n0, 0, Bs, tid);
  if (nk > 1) stage128(A, lda, m0, 64, Ab1, tid);

#pragma unroll 1
  for (int X = 0; X < nk; X += 2) {
    gstep32(A, lda, Bt, ldb, m0, n0, nk, X,     Ab0, Bs, tid, sk, aro, bro, acc);
    gstep32(A, lda, Bt, ldb, m0, n0, nk, X + 1, Ab1, Bs, tid, sk, aro, bro, acc);
  }
}

__global__ void cvt_x(const float* __restrict__ x, ushort* __restrict__ xb)
{
  const size_t i = (size_t)(blockIdx.x * 256 + threadIdx.x) * 4;
  const f32x4 t = *(const f32x4*)(x + i);
  uint2 pk;
  pk.x = (uint32_t)f2bf(t[0]) | ((uint32_t)f2bf(t[1]) << 16);
  pk.y = (uint32_t)f2bf(t[2]) | ((uint32_t)f2bf(t[3]) << 16);
  *(uint2*)(xb + i) = pk;
}

// wt[z][n][k] = bf16(w_z[k][n]);  z: 0=q_wei, 1=k_wei, 2=v_wei
__global__ void cvt_w(const float* __restrict__ kw, const float* __restrict__ qw,
                      const float* __restrict__ vw, ushort* __restrict__ wt)
{
  __shared__ float t[32][33];
  const float* w = (blockIdx.z == 0) ? qw : (blockIdx.z == 1) ? kw : vw;
  const int n0 = blockIdx.x * 32, k0 = blockIdx.y * 32;
  t[threadIdx.y][threadIdx.x] = w[(size_t)(k0 + threadIdx.y) * 1024 + n0 + threadIdx.x];
  __syncthreads();
  wt[(size_t)blockIdx.z * 1048576 + (size_t)(n0 + threadIdx.y) * 1024 + k0 + threadIdx.x] =
      f2bf(t[threadIdx.x][threadIdx.y]);
}

// N = 3072 (q|k|v), M = 16384. grid (24, 128) = 3072 blocks.
// Rect XCD map; 32x32x16 core; epilogue via C/D layout
// col=lane&31, row=(reg&3)+8*(reg>>2)+4*(lane>>5)  [m74/m101-verified].
__global__ __launch_bounds__(256) void gemm_qkv_impl(
    const ushort* __restrict__ xb, const ushort* __restrict__ wt,
    ushort* __restrict__ q, ushort* __restrict__ k, ushort* __restrict__ vT)
{
  extern __shared__ short lds[];
  const int flat = blockIdx.x + 24 * blockIdx.y;
  const int xcd = flat & 7, c = flat >> 3;          // c in [0,384)
  const int mloc = c / 6, nloc = c - mloc * 6;
  const int m0 = ((xcd & 1) * 64 + mloc) * 128;
  const int n0 = ((xcd >> 1) * 6 + nloc) * 128;
  f32x16 acc[2][2];
  gemm_core32(xb, 1024, wt, 1024, m0, n0, 16, lds, acc);

  const int tid  = threadIdx.x;
  const int lane = tid & 63;
  const int wid  = tid >> 6;
  const int wr = wid >> 1, wc = wid & 1;
  const int r31 = lane & 31, kh = lane >> 5;
  const int z  = n0 >> 10;                         // uniform per block

  if (z < 2) {
    ushort* o = (z == 0) ? q : k;
    const int cb = (n0 & 1023) + wc * 64 + r31;
#pragma unroll
    for (int mi = 0; mi < 2; ++mi)
#pragma unroll
      for (int ni = 0; ni < 2; ++ni)
#pragma unroll
        for (int r = 0; r < 16; ++r) {
          const int row = m0 + wr * 64 + mi * 32 + (r & 3) + 8 * (r >> 2) + 4 * kh;
          o[(size_t)row * 1024 + cb + ni * 32] = f2bf(acc[mi][ni][r]);
        }
  } else {
    // z==2: transpose in LDS (pad 136), then coalesced 16B stores along T
    // into vT[b][c][t].
    __syncthreads();                       // all waves done with staging LDS
    ushort* tr = (ushort*)lds;             // [128 c][136 r-pad]
#pragma unroll
    for (int mi = 0; mi < 2; ++mi)
#pragma unroll
      for (int ni = 0; ni < 2; ++ni)
#pragma unroll
        for (int r = 0; r < 16; ++r) {
          const int rl = wr * 64 + mi * 32 + (r & 3) + 8 * (r >> 2) + 4 * kh;
          const int cl = wc * 64 + ni * 32 + r31;
          tr[cl * 136 + rl] = f2bf(acc[mi][ni][r]);
        }
    __syncthreads();
    const int cl   = tid >> 1;
    const int half = tid & 1;
    const ushort* src = tr + cl * 136 + half * 64;
    ushort* dst = vT + ((size_t)(m0 >> 11) * 1024 + (n0 & 1023) + cl) * 2048
                     + (m0 & 2047) + half * 64;
#pragma unroll
    for (int i = 0; i < 8; ++i)
      *(s16x8*)(dst + i * 8) = *(const s16x8*)(src + i * 8);
  }
}

// Fused S-GEMM + softmax-exp (no-max trick): writes unnormalized
// P~ = exp(qk/32 - 10) bf16 dense [b][2048][2048], accumulates row sums.
// grid (16 kt, 16 qt, 8 b) = 2048 blocks; one b per XCD; causal tile skip;
// on diagonal tiles wave (wr0,wc1) is fully masked -> skipw.
__global__ __launch_bounds__(256) void gemm_sp(
    const ushort* __restrict__ q, const ushort* __restrict__ k,
    ushort* __restrict__ P, float* __restrict__ sums)
{
  extern __shared__ short lds[];
  const int nf = xcd_swz(blockIdx.x + 16 * (blockIdx.y + 16 * blockIdx.z), 256);
  const int kt = nf & 15, qt = (nf >> 4) & 15, b = nf >> 8;
  if (kt > qt) return;  // causal: whole tile masked
  const int tid  = threadIdx.x;
  const int lane = tid & 63, wid = tid >> 6;
  const int wr = wid >> 1, wc = wid & 1;
  const int diag = (kt == qt);
  const bool skipw = diag && (wr == 0) && (wc == 1);   // quadrant fully masked

  f32x4 acc[4][4];
  const ushort* qb = q + (size_t)b * (2048 * 1024);
  const ushort* kb = k + (size_t)b * (2048 * 1024);
  gemm_core(qb, 1024, kb, 1024, qt * 128, kt * 128, 16, lds, acc, skipw);
  __syncthreads();                          // staging LDS now dead; reuse below
  float* rowsum = (float*)lds;              // [2 wc][128 rows]

  const int q4 = (lane >> 4) << 2;
  const int fr = lane & 15;
  ushort* Pb = P + ((size_t)b << 22);

#pragma unroll
  for (int mi = 0; mi < 4; ++mi)
#pragma unroll
    for (int j = 0; j < 4; ++j) {
      const int rloc = wr * 64 + mi * 16 + q4 + j;       // row in tile
      const int rg   = qt * 128 + rloc;                   // global q index
      float s = 0.f;
#pragma unroll
      for (int ni = 0; ni < 4; ++ni) {
        const int cg = kt * 128 + wc * 64 + ni * 16 + fr; // global k index
        float e = __expf(acc[mi][ni][j] * 0.03125f - 10.f);
        if (diag && cg > rg) e = 0.f;
        s += e;
        Pb[(size_t)rg * 2048 + cg] = f2bf(e);
      }
      // reduce over the 16 fr lanes (this wave's 64-col stripe)
#pragma unroll
      for (int m = 1; m < 16; m <<= 1) s += __shfl_xor(s, m);
      if (fr == 0) rowsum[wc * 128 + rloc] = s;
    }
  __syncthreads();
  if (tid < 128) {
    const float tot = rowsum[tid] + rowsum[128 + tid];
    atomicAdd(&sums[b * 2048 + qt * 128 + tid], tot);
  }
}

// grid (8 ht, 16 qt, 8 b) = 1024 blocks; one b per XCD; K truncated causally;
// out = (P~ . V) / sums[row].
__global__ __launch_bounds__(256) void gemm_pv(
    const ushort* __restrict__ P, const ushort* __restrict__ vT,
    const float* __restrict__ sums, float* __restrict__ out)
{
  extern __shared__ short lds[];
  const int nf = xcd_swz(blockIdx.x + 8 * (blockIdx.y + 16 * blockIdx.z), 128);
  const int ht = nf & 7, qt = (nf >> 3) & 15, b = nf >> 7;
  f32x4 acc[4][4];
  const ushort* Pb = P  + ((size_t)b << 22);           // dense [2048][2048]
  const ushort* Vb = vT + (size_t)b * (1024 * 2048);
  gemm_core(Pb, 2048, Vb, 2048, qt * 128, ht * 128, (qt + 1) * 2, lds, acc);

  float* ob = out + (size_t)b * 2097152;
  const int lane = threadIdx.x & 63;
  const int wid = threadIdx.x >> 6;
  const int wr = wid >> 1, wc = wid & 1;
  const int r0 = qt * 128 + wr * 64 + ((lane >> 4) << 2);
  const int c0 = ht * 128 + wc * 64 + (lane & 15);
#pragma unroll
  for (int mi = 0; mi < 4; ++mi)
#pragma unroll
    for (int j = 0; j < 4; ++j) {
      const int r = r0 + mi * 16 + j;
      const float inv = 1.0f / sums[b * 2048 + r];
#pragma unroll
      for (int ni = 0; ni < 4; ++ni)
        ob[(size_t)r * 1024 + (c0 + ni * 16)] = acc[mi][ni][j] * inv;
    }
}

extern "C" void kernel_launch(void* const* d_in, const int* in_sizes, int n_in,
                              void* d_out, int out_size, void* d_ws, size_t ws_size,
                              hipStream_t stream)
{
  const float* x  = (const float*)d_in[0];
  const float* kw = (const float*)d_in[1];
  const float* qw = (const float*)d_in[2];
  const float* vw = (const float*)d_in[3];
  float* out = (float*)d_out;
  char* ws = (char*)d_ws;

  ushort* xb   = (ushort*)ws;                  // 32MB; aliases P~ (consumed first)
  ushort* P    = (ushort*)ws;                  // 64MB dense bf16 P~ [8][2048][2048]
  float*  sums = (float*)(ws + 67108864);      // 64KB row sums [8][2048]
  ushort* wt   = (ushort*)(ws + 67174400);     // 6MB  transposed bf16 weights [z][n][k]
  ushort* q    = (ushort*)(ws + 73465856);     // 32MB
  ushort* k    = (ushort*)(ws + 107020288);    // 32MB
  ushort* vT   = (ushort*)(ws + 140574720);    // 32MB [B][HS][T]

  const int LDSB = 49152;   // 48KB dynamic LDS (A dbuf + B single) -> 3 blocks/CU
  hipMemsetAsync(sums, 0, 8 * 2048 * sizeof(float), stream);
  cvt_x<<<16384, 256, 0, stream>>>(x, xb);
  cvt_w<<<dim3(32, 32, 3), dim3(32, 32), 0, stream>>>(kw, qw, vw, wt);
  gemm_qkv_impl<<<dim3(24, 128), 256, LDSB, stream>>>(xb, wt, q, k, vT);
  gemm_sp<<<dim3(16, 16, 8), 256, LDSB, stream>>>(q, k, P, sums);
  gemm_pv<<<dim3(8, 16, 8), 256, LDSB, stream>>>(P, vT, sums, out);
}

// Round 17
// 244.845 us; speedup vs baseline: 1.0499x; 1.0499x over previous
//
#include <hip/hip_runtime.h>
#include <hip/hip_bf16.h>
#include <stdint.h>

typedef __attribute__((ext_vector_type(4))) float f32x4;
typedef __attribute__((ext_vector_type(8))) short s16x8;

#define BARRIER() asm volatile("s_barrier" ::: "memory")
#define WAITV4()  asm volatile("s_waitcnt vmcnt(4)" ::: "memory")
#define WAITV0()  asm volatile("s_waitcnt vmcnt(0)" ::: "memory")
#define LGKM0()   asm volatile("s_waitcnt lgkmcnt(0)" ::: "memory")
#define MFMA(a, b, c) __builtin_amdgcn_mfma_f32_16x16x32_bf16((a), (b), (c), 0, 0, 0)

__device__ __forceinline__ ushort f2bf(float f) {
  union { float f; uint32_t u; } v; v.f = f;
  uint32_t r = v.u + 0x7FFFu + ((v.u >> 16) & 1u);
  return (ushort)(r >> 16);
}

__device__ __forceinline__ void gload_lds16(const ushort* g, short* l) {
  __builtin_amdgcn_global_load_lds(
      (const __attribute__((address_space(1))) uint32_t*)g,
      (__attribute__((address_space(3))) uint32_t*)l, 16, 0, 0);
}

// generic bijective XCD chunk swizzle; valid when nwg % 8 == 0, q = nwg/8
__device__ __forceinline__ int xcd_swz(int flat, int q) {
  return (flat & 7) * q + (flat >> 3);
}

// Stage a 128x64 bf16 tile into LDS with 256 threads (4 loads/thread).
// LDS dest linear (global_load_lds requirement); T2 swizzle via permuted
// GLOBAL source 16B-slot: phys(r,s) holds global(r, s ^ (r&7)).
__device__ __forceinline__ void stage128(const ushort* __restrict__ g, int ld,
                                         int row0, int k0, short* lbase, int tid) {
  const int w  = tid >> 6;
  const int l  = tid & 63;
  const int lr = l >> 3;
  const int ls = l & 7;
  const ushort* gp = g + (size_t)(row0 + lr) * ld + k0 + ((ls ^ lr) << 3);
  short* lp = lbase + l * 8;
#pragma unroll
  for (int i = 0; i < 4; ++i) {
    const int R0 = w * 32 + i * 8;
    gload_lds16(gp + (size_t)R0 * ld, lp + R0 * 64);
  }
}

// One K-step, 3-buffer ledger (A dbuf + B single = 48KB -> 3 blocks/CU,
// counted vmcnt preserved). Entering step X outstanding = {A(X),B(X),A(X+1)}
// (12 loads); WAITV4 keeps newest 4 = A(X+1)'s stage, drains A(X)+B(X).
// All frag reads at alpha; LGKM0+barrier seals them; then stage B(X+1)->Bs
// (single buf, safe) THEN A(X+2)->Ac (same-parity buf) so the kept-4 is
// always the A stage. MFMA half-2 is pure-register after the stages.
__device__ __forceinline__ void gstep(
    const ushort* __restrict__ A, int lda, const ushort* __restrict__ Bt, int ldb,
    int m0, int n0, int nk, int X, short* Ac, short* Bs,
    int tid, int s0, int aro, int bro, f32x4 acc[4][4], bool skipw)
{
  if (X + 1 < nk) { WAITV4(); } else { WAITV0(); }
  BARRIER();

  s16x8 b[4][2], a[4][2];
  if (!skipw) {
#pragma unroll
    for (int ni = 0; ni < 4; ++ni) {
      b[ni][0] = *(const s16x8*)(Bs + bro + ni * 1024 + s0);
      b[ni][1] = *(const s16x8*)(Bs + bro + ni * 1024 + (s0 ^ 32));
    }
#pragma unroll
    for (int mi = 0; mi < 4; ++mi) {
      a[mi][0] = *(const s16x8*)(Ac + aro + mi * 1024 + s0);
      a[mi][1] = *(const s16x8*)(Ac + aro + mi * 1024 + (s0 ^ 32));
    }
    __builtin_amdgcn_s_setprio(1);
#pragma unroll
    for (int mi = 0; mi < 2; ++mi)
#pragma unroll
      for (int ni = 0; ni < 4; ++ni) {
        acc[mi][ni] = MFMA(a[mi][0], b[ni][0], acc[mi][ni]);
        acc[mi][ni] = MFMA(a[mi][1], b[ni][1], acc[mi][ni]);
      }
    __builtin_amdgcn_s_setprio(0);
  }

  LGKM0();        // all Ac/Bs ds_reads retired before DMA overwrites land
  BARRIER();
  if (X + 1 < nk) stage128(Bt, ldb, n0, (X + 1) * 64, Bs, tid);   // B(X+1)
  if (X + 2 < nk) stage128(A, lda, m0, (X + 2) * 64, Ac, tid);    // A(X+2)
  if (!skipw) {
    __builtin_amdgcn_s_setprio(1);
#pragma unroll
    for (int mi = 0; mi < 2; ++mi)
#pragma unroll
      for (int ni = 0; ni < 4; ++ni) {
        acc[2 + mi][ni] = MFMA(a[2 + mi][0], b[ni][0], acc[2 + mi][ni]);
        acc[2 + mi][ni] = MFMA(a[2 + mi][1], b[ni][1], acc[2 + mi][ni]);
      }
    __builtin_amdgcn_s_setprio(0);
  }
}

// 128x128 tile GEMM core: A[M,K]*Bt[N,K]^T, bf16, fp32 acc. 256 thr = 4 waves
// (2M x 2N), wave = 64x64 = 4x4 frags. 48KB LDS (A dbuf + B single) ->
// 3 blocks/CU with counted vmcnt(4). REQUIRES nk even (16 / 16 / 2(qt+1)).
// skipw: wave-uniform MFMA/read skip for fully-masked quadrants.
__device__ __forceinline__ void gemm_core(
    const ushort* __restrict__ A, int lda, const ushort* __restrict__ Bt, int ldb,
    int m0, int n0, int nk, short* lds, f32x4 acc[4][4], bool skipw = false)
{
  const int tid  = threadIdx.x;
  const int lane = tid & 63, wid = tid >> 6;
  const int wr = wid >> 1, wc = wid & 1;
  const int fr = lane & 15, kg = lane >> 4;
  const int s0  = (kg ^ (fr & 7)) << 3;        // swizzled slot offset (shorts)
  const int aro = (wr * 64 + fr) * 64;
  const int bro = (wc * 64 + fr) * 64;

  short* Ab0 = lds;            // A even tiles
  short* Ab1 = lds + 8192;     // A odd tiles
  short* Bs  = lds + 16384;    // B single buffer

#pragma unroll
  for (int i = 0; i < 4; ++i)
#pragma unroll
    for (int j = 0; j < 4; ++j)
      acc[i][j] = (f32x4){0.f, 0.f, 0.f, 0.f};

  // prologue: A(0), B(0), A(1) in flight — A(1) issued LAST (kept by WAITV4)
  stage128(A, lda, m0, 0, Ab0, tid);
  stage128(Bt, ldb, n0, 0, Bs, tid);
  if (nk > 1) stage128(A, lda, m0, 64, Ab1, tid);

#pragma unroll 1
  for (int X = 0; X < nk; X += 2) {
    gstep(A, lda, Bt, ldb, m0, n0, nk, X,     Ab0, Bs, tid, s0, aro, bro, acc, skipw);
    gstep(A, lda, Bt, ldb, m0, n0, nk, X + 1, Ab1, Bs, tid, s0, aro, bro, acc, skipw);
  }
}

// 8 bf16/thread, 16B store. grid 8192 x 256.
__global__ void cvt_x(const float* __restrict__ x, ushort* __restrict__ xb)
{
  const size_t i = (size_t)(blockIdx.x * 256 + threadIdx.x) * 8;
  const f32x4 t0 = *(const f32x4*)(x + i);
  const f32x4 t1 = *(const f32x4*)(x + i + 4);
  uint4 pk;
  pk.x = (uint32_t)f2bf(t0[0]) | ((uint32_t)f2bf(t0[1]) << 16);
  pk.y = (uint32_t)f2bf(t0[2]) | ((uint32_t)f2bf(t0[3]) << 16);
  pk.z = (uint32_t)f2bf(t1[0]) | ((uint32_t)f2bf(t1[1]) << 16);
  pk.w = (uint32_t)f2bf(t1[2]) | ((uint32_t)f2bf(t1[3]) << 16);
  *(uint4*)(xb + i) = pk;
}

// wt[z][n][k] = bf16(w_z[k][n]);  z: 0=q_wei, 1=k_wei, 2=v_wei
__global__ void cvt_w(const float* __restrict__ kw, const float* __restrict__ qw,
                      const float* __restrict__ vw, ushort* __restrict__ wt)
{
  __shared__ float t[32][33];
  const float* w = (blockIdx.z == 0) ? qw : (blockIdx.z == 1) ? kw : vw;
  const int n0 = blockIdx.x * 32, k0 = blockIdx.y * 32;
  t[threadIdx.y][threadIdx.x] = w[(size_t)(k0 + threadIdx.y) * 1024 + n0 + threadIdx.x];
  __syncthreads();
  wt[(size_t)blockIdx.z * 1048576 + (size_t)(n0 + threadIdx.y) * 1024 + k0 + threadIdx.x] =
      f2bf(t[threadIdx.x][threadIdx.y]);
}

// N = 3072 (q|k|v), M = 16384. grid (24, 128) = 3072 blocks.
// Rect XCD map: 8 XCDs = 2 m-groups x 4 n-groups(6 tiles); per-XCD B-chunk
// 1.5MB L2-resident, A streams. z = n0>>10 uniform per block.
__global__ __launch_bounds__(256) void gemm_qkv_impl(
    const ushort* __restrict__ xb, const ushort* __restrict__ wt,
    ushort* __restrict__ q, ushort* __restrict__ k, ushort* __restrict__ vT)
{
  extern __shared__ short lds[];
  const int flat = blockIdx.x + 24 * blockIdx.y;
  const int xcd = flat & 7, c = flat >> 3;          // c in [0,384)
  const int mloc = c / 6, nloc = c - mloc * 6;
  const int m0 = ((xcd & 1) * 64 + mloc) * 128;
  const int n0 = ((xcd >> 1) * 6 + nloc) * 128;
  f32x4 acc[4][4];
  gemm_core(xb, 1024, wt, 1024, m0, n0, 16, lds, acc);

  const int tid  = threadIdx.x;
  const int lane = tid & 63;
  const int wid  = tid >> 6;
  const int wr = wid >> 1, wc = wid & 1;
  const int q4 = (lane >> 4) << 2;
  const int fr = lane & 15;
  const int z  = n0 >> 10;                         // uniform per block

  if (z < 2) {
    ushort* o = (z == 0) ? q : k;
    const int cb = (n0 & 1023) + wc * 64 + fr;
#pragma unroll
    for (int mi = 0; mi < 4; ++mi)
#pragma unroll
      for (int ni = 0; ni < 4; ++ni)
#pragma unroll
        for (int j = 0; j < 4; ++j) {
          const int r = m0 + wr * 64 + mi * 16 + q4 + j;
          o[(size_t)r * 1024 + cb + ni * 16] = f2bf(acc[mi][ni][j]);
        }
  } else {
    // z==2: transpose in LDS (pad 136 to spread banks), then coalesced 16B
    // stores along T into vT[b][c][t].
    __syncthreads();                       // all waves done with staging LDS
    ushort* tr = (ushort*)lds;             // [128 c][136 r-pad]
#pragma unroll
    for (int mi = 0; mi < 4; ++mi)
#pragma unroll
      for (int ni = 0; ni < 4; ++ni)
#pragma unroll
        for (int j = 0; j < 4; ++j) {
          const int cl = wc * 64 + ni * 16 + fr;
          const int rl = wr * 64 + mi * 16 + q4 + j;
          tr[cl * 136 + rl] = f2bf(acc[mi][ni][j]);
        }
    __syncthreads();
    const int cl   = tid >> 1;
    const int half = tid & 1;
    const ushort* src = tr + cl * 136 + half * 64;
    ushort* dst = vT + ((size_t)(m0 >> 11) * 1024 + (n0 & 1023) + cl) * 2048
                     + (m0 & 2047) + half * 64;
#pragma unroll
    for (int i = 0; i < 8; ++i)
      *(s16x8*)(dst + i * 8) = *(const s16x8*)(src + i * 8);
  }
}

// Fused S-GEMM + softmax-exp (no-max trick): writes unnormalized
// P~ = exp(qk/32 - 10) bf16 dense [b][2048][2048], accumulates row sums.
// grid (16 kt, 16 qt, 8 b) = 2048 blocks; one b per XCD; causal tile skip;
// on diagonal tiles wave (wr0,wc1) is fully masked -> skipw.
__global__ __launch_bounds__(256) void gemm_sp(
    const ushort* __restrict__ q, const ushort* __restrict__ k,
    ushort* __restrict__ P, float* __restrict__ sums)
{
  extern __shared__ short lds[];
  const int nf = xcd_swz(blockIdx.x + 16 * (blockIdx.y + 16 * blockIdx.z), 256);
  const int kt = nf & 15, qt = (nf >> 4) & 15, b = nf >> 8;
  if (kt > qt) return;  // causal: whole tile masked
  const int tid  = threadIdx.x;
  const int lane = tid & 63, wid = tid >> 6;
  const int wr = wid >> 1, wc = wid & 1;
  const int diag = (kt == qt);
  const bool skipw = diag && (wr == 0) && (wc == 1);   // quadrant fully masked

  f32x4 acc[4][4];
  const ushort* qb = q + (size_t)b * (2048 * 1024);
  const ushort* kb = k + (size_t)b * (2048 * 1024);
  gemm_core(qb, 1024, kb, 1024, qt * 128, kt * 128, 16, lds, acc, skipw);
  __syncthreads();                          // staging LDS now dead; reuse below
  float* rowsum = (float*)lds;              // [2 wc][128 rows]

  const int q4 = (lane >> 4) << 2;
  const int fr = lane & 15;
  ushort* Pb = P + ((size_t)b << 22);

#pragma unroll
  for (int mi = 0; mi < 4; ++mi)
#pragma unroll
    for (int j = 0; j < 4; ++j) {
      const int rloc = wr * 64 + mi * 16 + q4 + j;       // row in tile
      const int rg   = qt * 128 + rloc;                   // global q index
      float s = 0.f;
#pragma unroll
      for (int ni = 0; ni < 4; ++ni) {
        const int cg = kt * 128 + wc * 64 + ni * 16 + fr; // global k index
        float e = __expf(acc[mi][ni][j] * 0.03125f - 10.f);
        if (diag && cg > rg) e = 0.f;
        s += e;
        Pb[(size_t)rg * 2048 + cg] = f2bf(e);
      }
      // reduce over the 16 fr lanes (this wave's 64-col stripe)
#pragma unroll
      for (int m = 1; m < 16; m <<= 1) s += __shfl_xor(s, m);
      if (fr == 0) rowsum[wc * 128 + rloc] = s;
    }
  __syncthreads();
  if (tid < 128) {
    const float tot = rowsum[tid] + rowsum[128 + tid];
    atomicAdd(&sums[b * 2048 + qt * 128 + tid], tot);
  }
}

// grid (8 ht, 16 qt, 8 b) = 1024 blocks; one b per XCD; K truncated causally;
// out = (P~ . V) / sums[row].
__global__ __launch_bounds__(256) void gemm_pv(
    const ushort* __restrict__ P, const ushort* __restrict__ vT,
    const float* __restrict__ sums, float* __restrict__ out)
{
  extern __shared__ short lds[];
  const int nf = xcd_swz(blockIdx.x + 8 * (blockIdx.y + 16 * blockIdx.z), 128);
  const int ht = nf & 7, qt = (nf >> 3) & 15, b = nf >> 7;
  f32x4 acc[4][4];
  const ushort* Pb = P  + ((size_t)b << 22);           // dense [2048][2048]
  const ushort* Vb = vT + (size_t)b * (1024 * 2048);
  gemm_core(Pb, 2048, Vb, 2048, qt * 128, ht * 128, (qt + 1) * 2, lds, acc);

  float* ob = out + (size_t)b * 2097152;
  const int lane = threadIdx.x & 63;
  const int wid = threadIdx.x >> 6;
  const int wr = wid >> 1, wc = wid & 1;
  const int r0 = qt * 128 + wr * 64 + ((lane >> 4) << 2);
  const int c0 = ht * 128 + wc * 64 + (lane & 15);
#pragma unroll
  for (int mi = 0; mi < 4; ++mi)
#pragma unroll
    for (int j = 0; j < 4; ++j) {
      const int r = r0 + mi * 16 + j;
      const float inv = 1.0f / sums[b * 2048 + r];
#pragma unroll
      for (int ni = 0; ni < 4; ++ni)
        ob[(size_t)r * 1024 + (c0 + ni * 16)] = acc[mi][ni][j] * inv;
    }
}

extern "C" void kernel_launch(void* const* d_in, const int* in_sizes, int n_in,
                              void* d_out, int out_size, void* d_ws, size_t ws_size,
                              hipStream_t stream)
{
  const float* x  = (const float*)d_in[0];
  const float* kw = (const float*)d_in[1];
  const float* qw = (const float*)d_in[2];
  const float* vw = (const float*)d_in[3];
  float* out = (float*)d_out;
  char* ws = (char*)d_ws;

  ushort* xb   = (ushort*)ws;                  // 32MB; aliases P~ (consumed first)
  ushort* P    = (ushort*)ws;                  // 64MB dense bf16 P~ [8][2048][2048]
  float*  sums = (float*)(ws + 67108864);      // 64KB row sums [8][2048]
  ushort* wt   = (ushort*)(ws + 67174400);     // 6MB  transposed bf16 weights [z][n][k]
  ushort* q    = (ushort*)(ws + 73465856);     // 32MB
  ushort* k    = (ushort*)(ws + 107020288);    // 32MB
  ushort* vT   = (ushort*)(ws + 140574720);    // 32MB [B][HS][T]

  const int LDSB = 49152;   // 48KB dynamic LDS (A dbuf + B single) -> 3 blocks/CU
  hipMemsetAsync(sums, 0, 8 * 2048 * sizeof(float), stream);
  cvt_x<<<8192, 256, 0, stream>>>(x, xb);
  cvt_w<<<dim3(32, 32, 3), dim3(32, 32), 0, stream>>>(kw, qw, vw, wt);
  gemm_qkv_impl<<<dim3(24, 128), 256, LDSB, stream>>>(xb, wt, q, k, vT);
  gemm_sp<<<dim3(16, 16, 8), 256, LDSB, stream>>>(q, k, P, sums);
  gemm_pv<<<dim3(8, 16, 8), 256, LDSB, stream>>>(P, vT, sums, out);
}

// Round 18
// 242.796 us; speedup vs baseline: 1.0588x; 1.0084x over previous
//
#include <hip/hip_runtime.h>
#include <hip/hip_bf16.h>
#include <stdint.h>

typedef __attribute__((ext_vector_type(4))) float f32x4;
typedef __attribute__((ext_vector_type(8))) short s16x8;

#define BARRIER() asm volatile("s_barrier" ::: "memory")
#define WAITV4()  asm volatile("s_waitcnt vmcnt(4)" ::: "memory")
#define WAITV0()  asm volatile("s_waitcnt vmcnt(0)" ::: "memory")
#define LGKM0()   asm volatile("s_waitcnt lgkmcnt(0)" ::: "memory")
#define MFMA(a, b, c) __builtin_amdgcn_mfma_f32_16x16x32_bf16((a), (b), (c), 0, 0, 0)

__device__ __forceinline__ ushort f2bf(float f) {
  union { float f; uint32_t u; } v; v.f = f;
  uint32_t r = v.u + 0x7FFFu + ((v.u >> 16) & 1u);
  return (ushort)(r >> 16);
}

__device__ __forceinline__ void gload_lds16(const ushort* g, short* l) {
  __builtin_amdgcn_global_load_lds(
      (const __attribute__((address_space(1))) uint32_t*)g,
      (__attribute__((address_space(3))) uint32_t*)l, 16, 0, 0);
}

// generic bijective XCD chunk swizzle; valid when nwg % 8 == 0, q = nwg/8
__device__ __forceinline__ int xcd_swz(int flat, int q) {
  return (flat & 7) * q + (flat >> 3);
}

// Stage a 128x64 bf16 tile into LDS with 256 threads (4 loads/thread).
// LDS dest linear (global_load_lds requirement); T2 swizzle via permuted
// GLOBAL source 16B-slot: phys(r,s) holds global(r, s ^ (r&7)).
__device__ __forceinline__ void stage128(const ushort* __restrict__ g, int ld,
                                         int row0, int k0, short* lbase, int tid) {
  const int w  = tid >> 6;
  const int l  = tid & 63;
  const int lr = l >> 3;
  const int ls = l & 7;
  const ushort* gp = g + (size_t)(row0 + lr) * ld + k0 + ((ls ^ lr) << 3);
  short* lp = lbase + l * 8;
#pragma unroll
  for (int i = 0; i < 4; ++i) {
    const int R0 = w * 32 + i * 8;
    gload_lds16(gp + (size_t)R0 * ld, lp + R0 * 64);
  }
}

// One K-step, 3-buffer ledger (A dbuf + B single = 48KB -> 3 blocks/CU,
// counted vmcnt preserved). Entering step X outstanding = {A(X),B(X),A(X+1)}
// (12 loads); WAITV4 keeps newest 4 = A(X+1)'s stage, drains A(X)+B(X).
// All frag reads at alpha; LGKM0+barrier seals them; then stage B(X+1)->Bs
// (single buf, safe) THEN A(X+2)->Ac (same-parity buf) so the kept-4 is
// always the A stage. MFMA half-2 is pure-register after the stages.
__device__ __forceinline__ void gstep(
    const ushort* __restrict__ A, int lda, const ushort* __restrict__ Bt, int ldb,
    int m0, int n0, int nk, int X, short* Ac, short* Bs,
    int tid, int s0, int aro, int bro, f32x4 acc[4][4], bool skipw)
{
  if (X + 1 < nk) { WAITV4(); } else { WAITV0(); }
  BARRIER();

  s16x8 b[4][2], a[4][2];
  if (!skipw) {
#pragma unroll
    for (int ni = 0; ni < 4; ++ni) {
      b[ni][0] = *(const s16x8*)(Bs + bro + ni * 1024 + s0);
      b[ni][1] = *(const s16x8*)(Bs + bro + ni * 1024 + (s0 ^ 32));
    }
#pragma unroll
    for (int mi = 0; mi < 4; ++mi) {
      a[mi][0] = *(const s16x8*)(Ac + aro + mi * 1024 + s0);
      a[mi][1] = *(const s16x8*)(Ac + aro + mi * 1024 + (s0 ^ 32));
    }
    __builtin_amdgcn_s_setprio(1);
#pragma unroll
    for (int mi = 0; mi < 2; ++mi)
#pragma unroll
      for (int ni = 0; ni < 4; ++ni) {
        acc[mi][ni] = MFMA(a[mi][0], b[ni][0], acc[mi][ni]);
        acc[mi][ni] = MFMA(a[mi][1], b[ni][1], acc[mi][ni]);
      }
    __builtin_amdgcn_s_setprio(0);
  }

  LGKM0();        // all Ac/Bs ds_reads retired before DMA overwrites land
  BARRIER();
  if (X + 1 < nk) stage128(Bt, ldb, n0, (X + 1) * 64, Bs, tid);   // B(X+1)
  if (X + 2 < nk) stage128(A, lda, m0, (X + 2) * 64, Ac, tid);    // A(X+2)
  if (!skipw) {
    __builtin_amdgcn_s_setprio(1);
#pragma unroll
    for (int mi = 0; mi < 2; ++mi)
#pragma unroll
      for (int ni = 0; ni < 4; ++ni) {
        acc[2 + mi][ni] = MFMA(a[2 + mi][0], b[ni][0], acc[2 + mi][ni]);
        acc[2 + mi][ni] = MFMA(a[2 + mi][1], b[ni][1], acc[2 + mi][ni]);
      }
    __builtin_amdgcn_s_setprio(0);
  }
}

// 128x128 tile GEMM core: A[M,K]*Bt[N,K]^T, bf16, fp32 acc. 256 thr = 4 waves
// (2M x 2N), wave = 64x64 = 4x4 frags. 48KB LDS (A dbuf + B single) ->
// 3 blocks/CU with counted vmcnt(4). REQUIRES nk even (16 / 16 / 2(qt+1)).
// skipw: wave-uniform MFMA/read skip for fully-masked quadrants.
__device__ __forceinline__ void gemm_core(
    const ushort* __restrict__ A, int lda, const ushort* __restrict__ Bt, int ldb,
    int m0, int n0, int nk, short* lds, f32x4 acc[4][4], bool skipw = false)
{
  const int tid  = threadIdx.x;
  const int lane = tid & 63, wid = tid >> 6;
  const int wr = wid >> 1, wc = wid & 1;
  const int fr = lane & 15, kg = lane >> 4;
  const int s0  = (kg ^ (fr & 7)) << 3;        // swizzled slot offset (shorts)
  const int aro = (wr * 64 + fr) * 64;
  const int bro = (wc * 64 + fr) * 64;

  short* Ab0 = lds;            // A even tiles
  short* Ab1 = lds + 8192;     // A odd tiles
  short* Bs  = lds + 16384;    // B single buffer

#pragma unroll
  for (int i = 0; i < 4; ++i)
#pragma unroll
    for (int j = 0; j < 4; ++j)
      acc[i][j] = (f32x4){0.f, 0.f, 0.f, 0.f};

  // prologue: A(0), B(0), A(1) in flight — A(1) issued LAST (kept by WAITV4)
  stage128(A, lda, m0, 0, Ab0, tid);
  stage128(Bt, ldb, n0, 0, Bs, tid);
  if (nk > 1) stage128(A, lda, m0, 64, Ab1, tid);

#pragma unroll 1
  for (int X = 0; X < nk; X += 2) {
    gstep(A, lda, Bt, ldb, m0, n0, nk, X,     Ab0, Bs, tid, s0, aro, bro, acc, skipw);
    gstep(A, lda, Bt, ldb, m0, n0, nk, X + 1, Ab1, Bs, tid, s0, aro, bro, acc, skipw);
  }
}

// 8 bf16/thread, 16B store. grid 8192 x 256.
__global__ void cvt_x(const float* __restrict__ x, ushort* __restrict__ xb)
{
  const size_t i = (size_t)(blockIdx.x * 256 + threadIdx.x) * 8;
  const f32x4 t0 = *(const f32x4*)(x + i);
  const f32x4 t1 = *(const f32x4*)(x + i + 4);
  uint4 pk;
  pk.x = (uint32_t)f2bf(t0[0]) | ((uint32_t)f2bf(t0[1]) << 16);
  pk.y = (uint32_t)f2bf(t0[2]) | ((uint32_t)f2bf(t0[3]) << 16);
  pk.z = (uint32_t)f2bf(t1[0]) | ((uint32_t)f2bf(t1[1]) << 16);
  pk.w = (uint32_t)f2bf(t1[2]) | ((uint32_t)f2bf(t1[3]) << 16);
  *(uint4*)(xb + i) = pk;
}

// wt[z][n][k] = bf16(w_z[k][n]);  z: 0=q_wei, 1=k_wei, 2=v_wei
__global__ void cvt_w(const float* __restrict__ kw, const float* __restrict__ qw,
                      const float* __restrict__ vw, ushort* __restrict__ wt)
{
  __shared__ float t[32][33];
  const float* w = (blockIdx.z == 0) ? qw : (blockIdx.z == 1) ? kw : vw;
  const int n0 = blockIdx.x * 32, k0 = blockIdx.y * 32;
  t[threadIdx.y][threadIdx.x] = w[(size_t)(k0 + threadIdx.y) * 1024 + n0 + threadIdx.x];
  __syncthreads();
  wt[(size_t)blockIdx.z * 1048576 + (size_t)(n0 + threadIdx.y) * 1024 + k0 + threadIdx.x] =
      f2bf(t[threadIdx.x][threadIdx.y]);
}

// N = 3072 (q|k|v), M = 16384. grid (24, 128) = 3072 blocks.
// Rect XCD map: 8 XCDs = 2 m-groups x 4 n-groups(6 tiles); per-XCD B-chunk
// 1.5MB L2-resident, A streams. z = n0>>10 uniform per block.
__global__ __launch_bounds__(256) void gemm_qkv_impl(
    const ushort* __restrict__ xb, const ushort* __restrict__ wt,
    ushort* __restrict__ q, ushort* __restrict__ k, ushort* __restrict__ vT)
{
  extern __shared__ short lds[];
  const int flat = blockIdx.x + 24 * blockIdx.y;
  const int xcd = flat & 7, c = flat >> 3;          // c in [0,384)
  const int mloc = c / 6, nloc = c - mloc * 6;
  const int m0 = ((xcd & 1) * 64 + mloc) * 128;
  const int n0 = ((xcd >> 1) * 6 + nloc) * 128;
  f32x4 acc[4][4];
  gemm_core(xb, 1024, wt, 1024, m0, n0, 16, lds, acc);

  const int tid  = threadIdx.x;
  const int lane = tid & 63;
  const int wid  = tid >> 6;
  const int wr = wid >> 1, wc = wid & 1;
  const int q4 = (lane >> 4) << 2;
  const int fr = lane & 15;
  const int z  = n0 >> 10;                         // uniform per block

  if (z < 2) {
    ushort* o = (z == 0) ? q : k;
    const int cb = (n0 & 1023) + wc * 64 + fr;
#pragma unroll
    for (int mi = 0; mi < 4; ++mi)
#pragma unroll
      for (int ni = 0; ni < 4; ++ni)
#pragma unroll
        for (int j = 0; j < 4; ++j) {
          const int r = m0 + wr * 64 + mi * 16 + q4 + j;
          o[(size_t)r * 1024 + cb + ni * 16] = f2bf(acc[mi][ni][j]);
        }
  } else {
    // z==2: transpose in LDS (pad 136 to spread banks), then coalesced 16B
    // stores along T into vT[b][c][t].
    __syncthreads();                       // all waves done with staging LDS
    ushort* tr = (ushort*)lds;             // [128 c][136 r-pad]
#pragma unroll
    for (int mi = 0; mi < 4; ++mi)
#pragma unroll
      for (int ni = 0; ni < 4; ++ni)
#pragma unroll
        for (int j = 0; j < 4; ++j) {
          const int cl = wc * 64 + ni * 16 + fr;
          const int rl = wr * 64 + mi * 16 + q4 + j;
          tr[cl * 136 + rl] = f2bf(acc[mi][ni][j]);
        }
    __syncthreads();
    const int cl   = tid >> 1;
    const int half = tid & 1;
    const ushort* src = tr + cl * 136 + half * 64;
    ushort* dst = vT + ((size_t)(m0 >> 11) * 1024 + (n0 & 1023) + cl) * 2048
                     + (m0 & 2047) + half * 64;
#pragma unroll
    for (int i = 0; i < 8; ++i)
      *(s16x8*)(dst + i * 8) = *(const s16x8*)(src + i * 8);
  }
}

// Fused S-GEMM + softmax-exp (no-max trick): writes unnormalized
// P~ = exp(qk/32 - 10) bf16 dense [b][2048][2048], accumulates row sums.
// COMPACTED grid: 136 lower-triangle (qt,kt) pairs x 8 b = 1088 blocks
// (no dead upper-triangle dispatches). Triangle decode: qt via sqrt + fixup,
// kt fastest within qt (consecutive blocks share the q A-panel).
// On diagonal tiles wave (wr0,wc1) is fully masked -> skipw.
__global__ __launch_bounds__(256) void gemm_sp(
    const ushort* __restrict__ q, const ushort* __restrict__ k,
    ushort* __restrict__ P, float* __restrict__ sums)
{
  extern __shared__ short lds[];
  const int nf = xcd_swz(blockIdx.x + 136 * blockIdx.z, 136);
  const int t  = nf % 136;
  const int b  = nf / 136;
  int qt = (int)((sqrtf(8.0f * (float)t + 1.0f) - 1.0f) * 0.5f);
  while ((qt + 1) * (qt + 2) / 2 <= t) ++qt;   // fixup (float sqrt slop)
  while (qt * (qt + 1) / 2 > t) --qt;
  const int kt = t - qt * (qt + 1) / 2;

  const int tid  = threadIdx.x;
  const int lane = tid & 63, wid = tid >> 6;
  const int wr = wid >> 1, wc = wid & 1;
  const int diag = (kt == qt);
  const bool skipw = diag && (wr == 0) && (wc == 1);   // quadrant fully masked

  f32x4 acc[4][4];
  const ushort* qb = q + (size_t)b * (2048 * 1024);
  const ushort* kb = k + (size_t)b * (2048 * 1024);
  gemm_core(qb, 1024, kb, 1024, qt * 128, kt * 128, 16, lds, acc, skipw);
  __syncthreads();                          // staging LDS now dead; reuse below
  float* rowsum = (float*)lds;              // [2 wc][128 rows]

  const int q4 = (lane >> 4) << 2;
  const int fr = lane & 15;
  ushort* Pb = P + ((size_t)b << 22);

#pragma unroll
  for (int mi = 0; mi < 4; ++mi)
#pragma unroll
    for (int j = 0; j < 4; ++j) {
      const int rloc = wr * 64 + mi * 16 + q4 + j;       // row in tile
      const int rg   = qt * 128 + rloc;                   // global q index
      float s = 0.f;
#pragma unroll
      for (int ni = 0; ni < 4; ++ni) {
        const int cg = kt * 128 + wc * 64 + ni * 16 + fr; // global k index
        float e = __expf(acc[mi][ni][j] * 0.03125f - 10.f);
        if (diag && cg > rg) e = 0.f;
        s += e;
        Pb[(size_t)rg * 2048 + cg] = f2bf(e);
      }
      // reduce over the 16 fr lanes (this wave's 64-col stripe)
#pragma unroll
      for (int m = 1; m < 16; m <<= 1) s += __shfl_xor(s, m);
      if (fr == 0) rowsum[wc * 128 + rloc] = s;
    }
  __syncthreads();
  if (tid < 128) {
    const float tot = rowsum[tid] + rowsum[128 + tid];
    atomicAdd(&sums[b * 2048 + qt * 128 + tid], tot);
  }
}

// grid (8 ht, 16 qt, 8 b) = 1024 blocks; one b per XCD; K truncated causally;
// out = (P~ . V) / sums[row].
__global__ __launch_bounds__(256) void gemm_pv(
    const ushort* __restrict__ P, const ushort* __restrict__ vT,
    const float* __restrict__ sums, float* __restrict__ out)
{
  extern __shared__ short lds[];
  const int nf = xcd_swz(blockIdx.x + 8 * (blockIdx.y + 16 * blockIdx.z), 128);
  const int ht = nf & 7, qt = (nf >> 3) & 15, b = nf >> 7;
  f32x4 acc[4][4];
  const ushort* Pb = P  + ((size_t)b << 22);           // dense [2048][2048]
  const ushort* Vb = vT + (size_t)b * (1024 * 2048);
  gemm_core(Pb, 2048, Vb, 2048, qt * 128, ht * 128, (qt + 1) * 2, lds, acc);

  float* ob = out + (size_t)b * 2097152;
  const int lane = threadIdx.x & 63;
  const int wid = threadIdx.x >> 6;
  const int wr = wid >> 1, wc = wid & 1;
  const int r0 = qt * 128 + wr * 64 + ((lane >> 4) << 2);
  const int c0 = ht * 128 + wc * 64 + (lane & 15);
#pragma unroll
  for (int mi = 0; mi < 4; ++mi)
#pragma unroll
    for (int j = 0; j < 4; ++j) {
      const int r = r0 + mi * 16 + j;
      const float inv = 1.0f / sums[b * 2048 + r];
#pragma unroll
      for (int ni = 0; ni < 4; ++ni)
        ob[(size_t)r * 1024 + (c0 + ni * 16)] = acc[mi][ni][j] * inv;
    }
}

extern "C" void kernel_launch(void* const* d_in, const int* in_sizes, int n_in,
                              void* d_out, int out_size, void* d_ws, size_t ws_size,
                              hipStream_t stream)
{
  const float* x  = (const float*)d_in[0];
  const float* kw = (const float*)d_in[1];
  const float* qw = (const float*)d_in[2];
  const float* vw = (const float*)d_in[3];
  float* out = (float*)d_out;
  char* ws = (char*)d_ws;

  ushort* xb   = (ushort*)ws;                  // 32MB; aliases P~ (consumed first)
  ushort* P    = (ushort*)ws;                  // 64MB dense bf16 P~ [8][2048][2048]
  float*  sums = (float*)(ws + 67108864);      // 64KB row sums [8][2048]
  ushort* wt   = (ushort*)(ws + 67174400);     // 6MB  transposed bf16 weights [z][n][k]
  ushort* q    = (ushort*)(ws + 73465856);     // 32MB
  ushort* k    = (ushort*)(ws + 107020288);    // 32MB
  ushort* vT   = (ushort*)(ws + 140574720);    // 32MB [B][HS][T]

  const int LDSB = 49152;   // 48KB dynamic LDS (A dbuf + B single) -> 3 blocks/CU
  hipMemsetAsync(sums, 0, 8 * 2048 * sizeof(float), stream);
  cvt_x<<<8192, 256, 0, stream>>>(x, xb);
  cvt_w<<<dim3(32, 32, 3), dim3(32, 32), 0, stream>>>(kw, qw, vw, wt);
  gemm_qkv_impl<<<dim3(24, 128), 256, LDSB, stream>>>(xb, wt, q, k, vT);
  gemm_sp<<<dim3(136, 1, 8), 256, LDSB, stream>>>(q, k, P, sums);
  gemm_pv<<<dim3(8, 16, 8), 256, LDSB, stream>>>(P, vT, sums, out);
}